// Round 4
// baseline (643.749 us; speedup 1.0000x reference)
//
#include <hip/hip_runtime.h>
#include <cmath>

typedef __attribute__((ext_vector_type(8))) short bf16x8;
typedef __attribute__((ext_vector_type(4))) float f32x4;
typedef unsigned short u16;

#define ATTN_SCALE 0.25f

__device__ inline u16 f2bf(float x) {
    union { float f; unsigned u; } v; v.f = x;
    unsigned r = v.u + 0x7FFFu + ((v.u >> 16) & 1u);
    return (u16)(r >> 16);
}
__device__ inline float bf2f(u16 u) {
    union { unsigned u; float f; } v; v.u = ((unsigned)u) << 16; return v.f;
}
__device__ inline float fast_tanh(float x) {
    float xc = fminf(fmaxf(x, -15.f), 15.f);
    float t = __expf(2.f * xc);
    return (t - 1.f) * __builtin_amdgcn_rcpf(t + 1.f);
}

// ---------- CSR build ----------

__global__ __launch_bounds__(256) void hist_kernel(const int* __restrict__ dst,
                                                   int* __restrict__ counts, int E) {
    int i = blockIdx.x * 256 + threadIdx.x;
    if (i < E) atomicAdd(&counts[dst[i]], 1);
}

__global__ __launch_bounds__(256) void scan1(const int* __restrict__ counts,
                                             int* __restrict__ tmp, int* __restrict__ bsum, int N) {
    __shared__ int wsum[4];
    int b = blockIdx.x, t = threadIdx.x;
    int base = b * 1024 + t * 4;
    int v0 = (base + 0 < N) ? counts[base + 0] : 0;
    int v1 = (base + 1 < N) ? counts[base + 1] : 0;
    int v2 = (base + 2 < N) ? counts[base + 2] : 0;
    int v3 = (base + 3 < N) ? counts[base + 3] : 0;
    int p0 = v0, p1 = p0 + v1, p2 = p1 + v2, p3 = p2 + v3;
    int s = p3;
    int lane = t & 63, wid = t >> 6;
    int sc = s;
    #pragma unroll
    for (int d = 1; d < 64; d <<= 1) {
        int o = __shfl_up(sc, d);
        if (lane >= d) sc += o;
    }
    if (lane == 63) wsum[wid] = sc;
    __syncthreads();
    int wof = 0;
    #pragma unroll
    for (int i = 0; i < 4; ++i) if (i < wid) wof += wsum[i];
    int excl = wof + sc - s;
    if (base + 0 < N) tmp[base + 0] = excl + p0;
    if (base + 1 < N) tmp[base + 1] = excl + p1;
    if (base + 2 < N) tmp[base + 2] = excl + p2;
    if (base + 3 < N) tmp[base + 3] = excl + p3;
    if (t == 255) bsum[b] = wof + sc;
}

__global__ void scan2(int* __restrict__ bsum, int nb) {
    int t = threadIdx.x;
    int v = (t < nb) ? bsum[t] : 0;
    int sc = v;
    #pragma unroll
    for (int d = 1; d < 64; d <<= 1) {
        int o = __shfl_up(sc, d);
        if (t >= d) sc += o;
    }
    if (t < nb) bsum[t] = sc - v;
}

__global__ __launch_bounds__(256) void scan3(const int* __restrict__ tmp,
                                             const int* __restrict__ bsum,
                                             int* __restrict__ offsets, int N) {
    int i = blockIdx.x * 256 + threadIdx.x;
    if (i < N) offsets[i + 1] = tmp[i] + bsum[i >> 10];
    if (i == 0) offsets[0] = 0;
}

__global__ __launch_bounds__(256) void copy_kernel(const int* __restrict__ a,
                                                   int* __restrict__ b, int n) {
    int i = blockIdx.x * 256 + threadIdx.x;
    if (i < n) b[i] = a[i];
}

// scatter: pos[e] = slot in dst-CSR; srcp[slot] = src[e]
__global__ __launch_bounds__(256) void scatter_kernel(const int* __restrict__ dst,
                                                      const int* __restrict__ src,
                                                      int* __restrict__ cursor,
                                                      int* __restrict__ pos,
                                                      int* __restrict__ srcp, int E) {
    int i = blockIdx.x * 256 + threadIdx.x;
    if (i < E) {
        int p = atomicAdd(&cursor[dst[i]], 1);
        pos[i] = p;
        srcp[p] = src[i];
    }
}

// ---------- weight -> MFMA B-fragment (bf16, frag-linear) ----------
__global__ __launch_bounds__(256) void make_frag(const float* __restrict__ W,
                                                 short* __restrict__ out) {
    int id = blockIdx.x * 256 + threadIdx.x;
    if (id >= 2048) return;
    int l = id & 63, t16 = id >> 6;
    int kk = t16 & 3, n = t16 >> 2;
    int col = n * 16 + (l & 15);
    int k0 = kk * 32 + (l >> 4) * 8;
    #pragma unroll
    for (int j = 0; j < 8; ++j)
        out[id * 8 + j] = (short)f2bf(W[col * 128 + k0 + j]);
}

// ---------- qkv GEMM: 3 channels, bf16 outputs ----------

__global__ __launch_bounds__(256) void qkv_gemm(
    const float* __restrict__ X, const short* __restrict__ frag,
    const float* __restrict__ bias,
    u16* __restrict__ Y0, u16* __restrict__ Y1, u16* __restrict__ Y2, int R)
{
    __shared__ __align__(16) char lds[64 * 256];
    const int t = threadIdx.x;
    const int base = blockIdx.x * 64;
    for (int i = 0; i < 8; ++i) {
        int flat = i * 1024 + t * 4;
        int r = flat >> 7, k = flat & 127;
        float4 v = make_float4(0.f, 0.f, 0.f, 0.f);
        if (base + r < R) v = *reinterpret_cast<const float4*>(&X[(size_t)(base + r) * 128 + k]);
        ushort4 b;
        b.x = f2bf(v.x); b.y = f2bf(v.y); b.z = f2bf(v.z); b.w = f2bf(v.w);
        *reinterpret_cast<ushort4*>(lds + r * 256 + ((k * 2) ^ ((r & 15) << 4))) = b;
    }
    __syncthreads();
    const int w = t >> 6, l = t & 63, lr = l & 15, lg = l >> 4;
    const int rowbase = (w * 16 + lr) * 256, swz = lr << 4;
    bf16x8 afr[4];
    #pragma unroll
    for (int kk = 0; kk < 4; ++kk)
        afr[kk] = *reinterpret_cast<const bf16x8*>(lds + rowbase + ((kk * 64 + lg * 16) ^ swz));
    for (int ch = 0; ch < 3; ++ch) {
        const bf16x8* bf = reinterpret_cast<const bf16x8*>(frag + ch * 2048 * 8);
        f32x4 acc[8];
        #pragma unroll
        for (int n = 0; n < 8; ++n) acc[n] = (f32x4){0.f, 0.f, 0.f, 0.f};
        #pragma unroll
        for (int n = 0; n < 8; ++n)
            #pragma unroll
            for (int kk = 0; kk < 4; ++kk)
                acc[n] = __builtin_amdgcn_mfma_f32_16x16x32_bf16(afr[kk], bf[(n * 4 + kk) * 64 + l],
                                                                 acc[n], 0, 0, 0);
        u16* Y = (ch == 0) ? Y0 : (ch == 1) ? Y1 : Y2;
        #pragma unroll
        for (int n = 0; n < 8; ++n) {
            int col = n * 16 + lr;
            float bv = bias[ch * 128 + col];
            #pragma unroll
            for (int reg = 0; reg < 4; ++reg) {
                int r = base + w * 16 + lg * 4 + reg;
                if (r < R) Y[(size_t)r * 128 + col] = f2bf(acc[n][reg] + bv);
            }
        }
    }
}

// ---------- generic rows x 128 @ 128x128 MFMA GEMM, f32 out (hproj) ----------

__global__ __launch_bounds__(256) void gemm128(
    const float* __restrict__ X, const short* __restrict__ frag,
    const float* __restrict__ bias, float* __restrict__ Y, int R)
{
    __shared__ __align__(16) char lds[64 * 256];
    const int t = threadIdx.x;
    const int base = blockIdx.x * 64;
    for (int i = 0; i < 8; ++i) {
        int flat = i * 1024 + t * 4;
        int r = flat >> 7, k = flat & 127;
        float4 v = make_float4(0.f, 0.f, 0.f, 0.f);
        if (base + r < R) v = *reinterpret_cast<const float4*>(&X[(size_t)(base + r) * 128 + k]);
        ushort4 b;
        b.x = f2bf(v.x); b.y = f2bf(v.y); b.z = f2bf(v.z); b.w = f2bf(v.w);
        *reinterpret_cast<ushort4*>(lds + r * 256 + ((k * 2) ^ ((r & 15) << 4))) = b;
    }
    __syncthreads();
    const int w = t >> 6, l = t & 63, lr = l & 15, lg = l >> 4;
    const int rowbase = (w * 16 + lr) * 256, swz = lr << 4;
    bf16x8 afr[4];
    #pragma unroll
    for (int kk = 0; kk < 4; ++kk)
        afr[kk] = *reinterpret_cast<const bf16x8*>(lds + rowbase + ((kk * 64 + lg * 16) ^ swz));
    const bf16x8* bf = reinterpret_cast<const bf16x8*>(frag);
    f32x4 acc[8];
    #pragma unroll
    for (int n = 0; n < 8; ++n) acc[n] = (f32x4){0.f, 0.f, 0.f, 0.f};
    #pragma unroll
    for (int n = 0; n < 8; ++n)
        #pragma unroll
        for (int kk = 0; kk < 4; ++kk)
            acc[n] = __builtin_amdgcn_mfma_f32_16x16x32_bf16(afr[kk], bf[(n * 4 + kk) * 64 + l],
                                                             acc[n], 0, 0, 0);
    #pragma unroll
    for (int n = 0; n < 8; ++n) {
        int col = n * 16 + lr;
        float bv = bias[col];
        #pragma unroll
        for (int reg = 0; reg < 4; ++reg) {
            int r = base + w * 16 + lg * 4 + reg;
            if (r < R) Y[(size_t)r * 128 + col] = acc[n][reg] + bv;
        }
    }
}

// ---------- fused edge kernel (MFMA bf16, prefetched gathers) ----------

__global__ __launch_bounds__(256, 4) void edge_mfma(
    const float* __restrict__ e, const int* __restrict__ src, const int* __restrict__ dst,
    const int* __restrict__ pos,
    const short* __restrict__ cfrag, const float* __restrict__ cbias,
    const short* __restrict__ efrag, const float* __restrict__ ebias,
    const u16* __restrict__ qbh, const u16* __restrict__ kbh,
    float* __restrict__ e_out, float* __restrict__ mean_out,
    float* __restrict__ logitp, int E)
{
    __shared__ __align__(16) char lds[64 * 256];
    const int t = threadIdx.x;
    const int base = blockIdx.x * 64;

    // stage e tile as bf16, swizzled: byte ^= (row&15)<<4
    for (int i = 0; i < 8; ++i) {
        int flat = i * 1024 + t * 4;
        int r = flat >> 7, k = flat & 127;
        float4 v = make_float4(0.f, 0.f, 0.f, 0.f);
        if (base + r < E) v = *reinterpret_cast<const float4*>(&e[(size_t)(base + r) * 128 + k]);
        ushort4 b;
        b.x = f2bf(v.x); b.y = f2bf(v.y); b.z = f2bf(v.z); b.w = f2bf(v.w);
        *reinterpret_cast<ushort4*>(lds + r * 256 + ((k * 2) ^ ((r & 15) << 4))) = b;
    }

    const int w = t >> 6, l = t & 63;
    const int lr = l & 15, lg = l >> 4;
    const int rowbase = (w * 16 + lr) * 256;
    const int swz = lr << 4;

    // edge ids + indices (independent of LDS)
    int er[4], si[4], di[4], po[4];
    bool vld[4];
    #pragma unroll
    for (int reg = 0; reg < 4; ++reg) {
        int ei = base + w * 16 + lg * 4 + reg;
        vld[reg] = ei < E;
        int ce = vld[reg] ? ei : (E - 1);
        er[reg] = ei;
        si[reg] = src[ce];
        di[reg] = dst[ce];
        po[reg] = pos[ce];
    }
    // prefetch batch A (heads 0..3): latency hides under staging drain + barrier
    u16 kA[4][4], qA[4][4];
    #pragma unroll
    for (int n = 0; n < 4; ++n)
        #pragma unroll
        for (int reg = 0; reg < 4; ++reg) {
            kA[n][reg] = kbh[(size_t)si[reg] * 128 + n * 16 + lr];
            qA[n][reg] = qbh[(size_t)di[reg] * 128 + n * 16 + lr];
        }

    __syncthreads();

    bf16x8 afr[4];
    #pragma unroll
    for (int kk = 0; kk < 4; ++kk)
        afr[kk] = *reinterpret_cast<const bf16x8*>(lds + rowbase + ((kk * 64 + lg * 16) ^ swz));

    const bf16x8* cf = reinterpret_cast<const bf16x8*>(cfrag);
    f32x4 acc[8];
    #pragma unroll
    for (int n = 0; n < 8; ++n) acc[n] = (f32x4){0.f, 0.f, 0.f, 0.f};
    #pragma unroll
    for (int n = 0; n < 8; ++n)
        #pragma unroll
        for (int kk = 0; kk < 4; ++kk)
            acc[n] = __builtin_amdgcn_mfma_f32_16x16x32_bf16(afr[kk], cf[(n * 4 + kk) * 64 + l],
                                                             acc[n], 0, 0, 0);

    // prefetch batch B (heads 4..7): latency hides under epilogue A
    u16 kB[4][4], qB[4][4];
    #pragma unroll
    for (int n = 0; n < 4; ++n)
        #pragma unroll
        for (int reg = 0; reg < 4; ++reg) {
            kB[n][reg] = kbh[(size_t)si[reg] * 128 + (n + 4) * 16 + lr];
            qB[n][reg] = qbh[(size_t)di[reg] * 128 + (n + 4) * 16 + lr];
        }

    // epilogue: tanh -> score -> bf16 LDS; head-mean accum
    float macc[4] = {0.f, 0.f, 0.f, 0.f};
    #pragma unroll
    for (int n = 0; n < 8; ++n) {
        const int col = n * 16 + lr;
        const float cb = cbias[col];
        #pragma unroll
        for (int reg = 0; reg < 4; ++reg) {
            float kv = bf2f(n < 4 ? kA[n & 3][reg] : kB[n & 3][reg]);
            float qv = bf2f(n < 4 ? qA[n & 3][reg] : qB[n & 3][reg]);
            float sc = fast_tanh(acc[n][reg] + cb) * kv * qv;
            macc[reg] += sc;
            int row = w * 16 + lg * 4 + reg;
            *reinterpret_cast<u16*>(
                lds + row * 256 + ((col * 2) ^ ((row & 15) << 4))) = f2bf(sc);
        }
    }
    #pragma unroll
    for (int reg = 0; reg < 4; ++reg)
        if (vld[reg]) mean_out[(size_t)er[reg] * 16 + lr] = macc[reg] * 0.125f;

    // A-frags from score (in-wave LDS ordering)
    bf16x8 afr2[4];
    #pragma unroll
    for (int kk = 0; kk < 4; ++kk)
        afr2[kk] = *reinterpret_cast<const bf16x8*>(lds + rowbase + ((kk * 64 + lg * 16) ^ swz));

    // logit via indicator-MFMA: B[k][h] = (k>>4 == h)
    bf16x8 ind[4];
    #pragma unroll
    for (int kk = 0; kk < 4; ++kk)
        #pragma unroll
        for (int j = 0; j < 8; ++j)
            ind[kk][j] = ((kk * 32 + lg * 8 + j) >> 4 == lr) ? (short)0x3F80 : (short)0;
    f32x4 lac = (f32x4){0.f, 0.f, 0.f, 0.f};
    #pragma unroll
    for (int kk = 0; kk < 4; ++kk)
        lac = __builtin_amdgcn_mfma_f32_16x16x32_bf16(afr2[kk], ind[kk], lac, 0, 0, 0);
    if (lr < 8) {
        #pragma unroll
        for (int reg = 0; reg < 4; ++reg)
            if (vld[reg]) logitp[(size_t)po[reg] * 8 + lr] = lac[reg] * ATTN_SCALE;
    }

    // GEMM2: e_out = score @ eproj_w.T
    const bf16x8* ef = reinterpret_cast<const bf16x8*>(efrag);
    f32x4 acc2[8];
    #pragma unroll
    for (int n = 0; n < 8; ++n) acc2[n] = (f32x4){0.f, 0.f, 0.f, 0.f};
    #pragma unroll
    for (int n = 0; n < 8; ++n)
        #pragma unroll
        for (int kk = 0; kk < 4; ++kk)
            acc2[n] = __builtin_amdgcn_mfma_f32_16x16x32_bf16(afr2[kk], ef[(n * 4 + kk) * 64 + l],
                                                              acc2[n], 0, 0, 0);

    // e_out roundtrip: bf16 -> LDS -> coalesced float4 stores
    #pragma unroll
    for (int n = 0; n < 8; ++n) {
        const int col = n * 16 + lr;
        const float eb = ebias[col];
        #pragma unroll
        for (int reg = 0; reg < 4; ++reg) {
            int row = w * 16 + lg * 4 + reg;
            *reinterpret_cast<u16*>(
                lds + row * 256 + ((col * 2) ^ ((row & 15) << 4))) = f2bf(acc2[n][reg] + eb);
        }
    }
    #pragma unroll
    for (int rh = 0; rh < 2; ++rh) {
        #pragma unroll
        for (int ih = 0; ih < 2; ++ih) {
            int row = w * 16 + (l >> 3) + 8 * rh;
            int col = (l & 7) * 8 + 64 * ih;
            bf16x8 sv = *reinterpret_cast<const bf16x8*>(
                lds + row * 256 + ((col * 2) ^ ((row & 15) << 4)));
            float4 o0, o1;
            o0.x = bf2f((u16)sv[0]); o0.y = bf2f((u16)sv[1]);
            o0.z = bf2f((u16)sv[2]); o0.w = bf2f((u16)sv[3]);
            o1.x = bf2f((u16)sv[4]); o1.y = bf2f((u16)sv[5]);
            o1.z = bf2f((u16)sv[6]); o1.w = bf2f((u16)sv[7]);
            if (base + row < E) {
                *reinterpret_cast<float4*>(&e_out[(size_t)(base + row) * 128 + col]) = o0;
                *reinterpret_cast<float4*>(&e_out[(size_t)(base + row) * 128 + col + 4]) = o1;
            }
        }
    }
}

// ---------- per-node softmax + aggregation ----------
// srcp/logitp are CSR-ordered -> staging reads fully coalesced.

__global__ __launch_bounds__(256) void node_kernel(
    const int* __restrict__ offsets, const int* __restrict__ srcp,
    const float* __restrict__ logitp, const u16* __restrict__ vbh,
    float* __restrict__ hagg, int N)
{
    __shared__ int   ls_src[4][64];
    __shared__ float ls_l[4][64][8];
    const int t = threadIdx.x, w = t >> 6, lane = t & 63;
    const int node = blockIdx.x * 4 + w;
    int off = 0, deg = 0;
    if (node < N) { off = offsets[node]; deg = offsets[node + 1] - off; }

    const int h = lane & 7, g = lane >> 3;
    float m = -3.0e38f, s = 0.f;

    for (int c0 = 0; c0 < deg; c0 += 64) {
        int cnt = min(64, deg - c0);
        if (lane < cnt) {
            ls_src[w][lane] = srcp[off + c0 + lane];
            float4 l0 = *reinterpret_cast<const float4*>(&logitp[(size_t)(off + c0 + lane) * 8]);
            float4 l1 = *reinterpret_cast<const float4*>(&logitp[(size_t)(off + c0 + lane) * 8 + 4]);
            *reinterpret_cast<float4*>(&ls_l[w][lane][0]) = l0;
            *reinterpret_cast<float4*>(&ls_l[w][lane][4]) = l1;
        }
        __asm__ __volatile__("s_waitcnt lgkmcnt(0)" ::: "memory");
        float cm = -3.0e38f;
        for (int j = g; j < cnt; j += 8) cm = fmaxf(cm, ls_l[w][j][h]);
        cm = fmaxf(cm, __shfl_xor(cm, 8));
        cm = fmaxf(cm, __shfl_xor(cm, 16));
        cm = fmaxf(cm, __shfl_xor(cm, 32));
        float mn = fmaxf(m, cm);
        float cs = 0.f;
        for (int j = g; j < cnt; j += 8) cs += __expf(ls_l[w][j][h] - mn);
        cs += __shfl_xor(cs, 8); cs += __shfl_xor(cs, 16); cs += __shfl_xor(cs, 32);
        s = s * __expf(m - mn) + cs;
        m = mn;
    }
    float inv = (deg > 0) ? 1.f / s : 0.f;

    float a0 = 0.f, a1 = 0.f;
    const int d0 = lane, d1 = lane + 64, h0 = lane >> 4, h1 = 4 + h0;
    for (int c0 = 0; c0 < deg; c0 += 64) {
        int cnt = min(64, deg - c0);
        if (deg > 64 && lane < cnt) {
            ls_src[w][lane] = srcp[off + c0 + lane];
            float4 l0 = *reinterpret_cast<const float4*>(&logitp[(size_t)(off + c0 + lane) * 8]);
            float4 l1 = *reinterpret_cast<const float4*>(&logitp[(size_t)(off + c0 + lane) * 8 + 4]);
            *reinterpret_cast<float4*>(&ls_l[w][lane][0]) = l0;
            *reinterpret_cast<float4*>(&ls_l[w][lane][4]) = l1;
        }
        __asm__ __volatile__("s_waitcnt lgkmcnt(0)" ::: "memory");
        for (int j = g; j < cnt; j += 8)
            ls_l[w][j][h] = __expf(ls_l[w][j][h] - m) * inv;
        __asm__ __volatile__("s_waitcnt lgkmcnt(0)" ::: "memory");
        #pragma unroll 4
        for (int j = 0; j < cnt; ++j) {
            int sn = ls_src[w][j];
            float w0 = ls_l[w][j][h0], w1 = ls_l[w][j][h1];
            a0 += w0 * bf2f(vbh[(size_t)sn * 128 + d0]);
            a1 += w1 * bf2f(vbh[(size_t)sn * 128 + d1]);
        }
    }
    if (node < N) {
        hagg[(size_t)node * 128 + d0] = a0;
        hagg[(size_t)node * 128 + d1] = a1;
    }
}

// ---------- launcher ----------

extern "C" void kernel_launch(void* const* d_in, const int* in_sizes, int n_in,
                              void* d_out, int out_size, void* d_ws, size_t ws_size,
                              hipStream_t stream)
{
    const float* h       = (const float*)d_in[0];
    const float* e       = (const float*)d_in[1];
    const int*   src     = (const int*)d_in[2];
    const int*   dst     = (const int*)d_in[3];
    const float* qkv_w   = (const float*)d_in[4];
    const float* qkv_b   = (const float*)d_in[5];
    const float* c_w     = (const float*)d_in[6];
    const float* c_b     = (const float*)d_in[7];
    const float* hproj_w = (const float*)d_in[8];
    const float* hproj_b = (const float*)d_in[9];
    const float* eproj_w = (const float*)d_in[10];
    const float* eproj_b = (const float*)d_in[11];

    const int N = in_sizes[0] / 128;
    const int E = in_sizes[1] / 128;

    float* h_out    = (float*)d_out;
    float* e_out    = h_out + (size_t)N * 128;
    float* mean_out = e_out + (size_t)E * 128;

    char* wp = (char*)d_ws;
    auto alloc = [&](size_t b) {
        void* p = (void*)wp;
        wp += (b + 255) & ~(size_t)255;
        return p;
    };
    short* qkvfrag = (short*)alloc(sizeof(short) * 3 * 2048 * 8);
    short* cfragb  = (short*)alloc(sizeof(short) * 2048 * 8);
    short* efragb  = (short*)alloc(sizeof(short) * 2048 * 8);
    short* hpfrag  = (short*)alloc(sizeof(short) * 2048 * 8);
    u16*   qbh     = (u16*)alloc(sizeof(u16) * (size_t)N * 128);
    u16*   kbh     = (u16*)alloc(sizeof(u16) * (size_t)N * 128);
    u16*   vbh     = (u16*)alloc(sizeof(u16) * (size_t)N * 128);
    float* hagg    = (float*)alloc(sizeof(float) * (size_t)N * 128);
    float* logitp  = (float*)alloc(sizeof(float) * (size_t)E * 8);
    int*   counts  = (int*)alloc(sizeof(int) * (N + 1));
    int*   offs    = (int*)alloc(sizeof(int) * (N + 1));
    int*   cursor  = (int*)alloc(sizeof(int) * (N + 1));
    int*   stmp    = (int*)alloc(sizeof(int) * (N + 1));
    int*   bsum    = (int*)alloc(sizeof(int) * 64);
    int*   pos     = (int*)alloc(sizeof(int) * E);
    int*   srcp    = (int*)alloc(sizeof(int) * E);

    hipMemsetAsync(counts, 0, sizeof(int) * (N + 1), stream);

    make_frag<<<8, 256, 0, stream>>>(qkv_w, qkvfrag);
    make_frag<<<8, 256, 0, stream>>>(qkv_w + 128 * 128, qkvfrag + 2048 * 8);
    make_frag<<<8, 256, 0, stream>>>(qkv_w + 2 * 128 * 128, qkvfrag + 2 * 2048 * 8);
    make_frag<<<8, 256, 0, stream>>>(c_w, cfragb);
    make_frag<<<8, 256, 0, stream>>>(eproj_w, efragb);
    make_frag<<<8, 256, 0, stream>>>(hproj_w, hpfrag);

    qkv_gemm<<<(N + 63) / 64, 256, 0, stream>>>(h, qkvfrag, qkv_b, qbh, kbh, vbh, N);

    hist_kernel<<<(E + 255) / 256, 256, 0, stream>>>(dst, counts, E);
    int nb = (N + 1023) / 1024;
    scan1<<<nb, 256, 0, stream>>>(counts, stmp, bsum, N);
    scan2<<<1, 64, 0, stream>>>(bsum, nb);
    scan3<<<(N + 255) / 256, 256, 0, stream>>>(stmp, bsum, offs, N);
    copy_kernel<<<(N + 256) / 256, 256, 0, stream>>>(offs, cursor, N + 1);
    scatter_kernel<<<(E + 255) / 256, 256, 0, stream>>>(dst, src, cursor, pos, srcp, E);

    edge_mfma<<<(E + 63) / 64, 256, 0, stream>>>(e, src, dst, pos, cfragb, c_b, efragb,
                                                 eproj_b, qbh, kbh, e_out, mean_out, logitp, E);

    node_kernel<<<(N + 3) / 4, 256, 0, stream>>>(offs, srcp, logitp, vbh, hagg, N);

    gemm128<<<(N + 63) / 64, 256, 0, stream>>>(hagg, hpfrag, hproj_b, h_out, N);
}

// Round 5
// 559.090 us; speedup vs baseline: 1.1514x; 1.1514x over previous
//
#include <hip/hip_runtime.h>
#include <cmath>

typedef __attribute__((ext_vector_type(8))) short bf16x8;
typedef __attribute__((ext_vector_type(4))) float f32x4;
typedef unsigned short u16;

#define ATTN_SCALE 0.25f

__device__ inline u16 f2bf(float x) {
    union { float f; unsigned u; } v; v.f = x;
    unsigned r = v.u + 0x7FFFu + ((v.u >> 16) & 1u);
    return (u16)(r >> 16);
}
__device__ inline float bf2f(u16 u) {
    union { unsigned u; float f; } v; v.u = ((unsigned)u) << 16; return v.f;
}
__device__ inline float fast_tanh(float x) {
    float xc = fminf(fmaxf(x, -15.f), 15.f);
    float t = __expf(2.f * xc);
    return (t - 1.f) * __builtin_amdgcn_rcpf(t + 1.f);
}

// ---------- CSR build ----------

__global__ __launch_bounds__(256) void hist_kernel(const int* __restrict__ dst,
                                                   int* __restrict__ counts, int E) {
    int i = blockIdx.x * 256 + threadIdx.x;
    if (i < E) atomicAdd(&counts[dst[i]], 1);
}

__global__ __launch_bounds__(256) void scan1(const int* __restrict__ counts,
                                             int* __restrict__ tmp, int* __restrict__ bsum, int N) {
    __shared__ int wsum[4];
    int b = blockIdx.x, t = threadIdx.x;
    int base = b * 1024 + t * 4;
    int v0 = (base + 0 < N) ? counts[base + 0] : 0;
    int v1 = (base + 1 < N) ? counts[base + 1] : 0;
    int v2 = (base + 2 < N) ? counts[base + 2] : 0;
    int v3 = (base + 3 < N) ? counts[base + 3] : 0;
    int p0 = v0, p1 = p0 + v1, p2 = p1 + v2, p3 = p2 + v3;
    int s = p3;
    int lane = t & 63, wid = t >> 6;
    int sc = s;
    #pragma unroll
    for (int d = 1; d < 64; d <<= 1) {
        int o = __shfl_up(sc, d);
        if (lane >= d) sc += o;
    }
    if (lane == 63) wsum[wid] = sc;
    __syncthreads();
    int wof = 0;
    #pragma unroll
    for (int i = 0; i < 4; ++i) if (i < wid) wof += wsum[i];
    int excl = wof + sc - s;
    if (base + 0 < N) tmp[base + 0] = excl + p0;
    if (base + 1 < N) tmp[base + 1] = excl + p1;
    if (base + 2 < N) tmp[base + 2] = excl + p2;
    if (base + 3 < N) tmp[base + 3] = excl + p3;
    if (t == 255) bsum[b] = wof + sc;
}

__global__ void scan2(int* __restrict__ bsum, int nb) {
    int t = threadIdx.x;
    int v = (t < nb) ? bsum[t] : 0;
    int sc = v;
    #pragma unroll
    for (int d = 1; d < 64; d <<= 1) {
        int o = __shfl_up(sc, d);
        if (t >= d) sc += o;
    }
    if (t < nb) bsum[t] = sc - v;
}

__global__ __launch_bounds__(256) void scan3(const int* __restrict__ tmp,
                                             const int* __restrict__ bsum,
                                             int* __restrict__ offsets, int N) {
    int i = blockIdx.x * 256 + threadIdx.x;
    if (i < N) offsets[i + 1] = tmp[i] + bsum[i >> 10];
    if (i == 0) offsets[0] = 0;
}

__global__ __launch_bounds__(256) void copy_kernel(const int* __restrict__ a,
                                                   int* __restrict__ b, int n) {
    int i = blockIdx.x * 256 + threadIdx.x;
    if (i < n) b[i] = a[i];
}

__global__ __launch_bounds__(256) void scatter_kernel(const int* __restrict__ dst,
                                                      int* __restrict__ cursor,
                                                      int* __restrict__ eidx, int E) {
    int i = blockIdx.x * 256 + threadIdx.x;
    if (i < E) {
        int p = atomicAdd(&cursor[dst[i]], 1);
        eidx[p] = i;
    }
}

// ---------- weight -> MFMA B-fragment (bf16, frag-linear) ----------
__global__ __launch_bounds__(256) void make_frag(const float* __restrict__ W,
                                                 short* __restrict__ out) {
    int id = blockIdx.x * 256 + threadIdx.x;
    if (id >= 2048) return;
    int l = id & 63, t16 = id >> 6;
    int kk = t16 & 3, n = t16 >> 2;
    int col = n * 16 + (l & 15);
    int k0 = kk * 32 + (l >> 4) * 8;
    #pragma unroll
    for (int j = 0; j < 8; ++j)
        out[id * 8 + j] = (short)f2bf(W[col * 128 + k0 + j]);
}

// ---------- qkv GEMM: 3 channels, bf16 outputs ----------

__global__ __launch_bounds__(256) void qkv_gemm(
    const float* __restrict__ X, const short* __restrict__ frag,
    const float* __restrict__ bias,
    u16* __restrict__ Y0, u16* __restrict__ Y1, u16* __restrict__ Y2, int R)
{
    __shared__ __align__(16) char lds[64 * 256];
    const int t = threadIdx.x;
    const int base = blockIdx.x * 64;
    for (int i = 0; i < 8; ++i) {
        int flat = i * 1024 + t * 4;
        int r = flat >> 7, k = flat & 127;
        float4 v = make_float4(0.f, 0.f, 0.f, 0.f);
        if (base + r < R) v = *reinterpret_cast<const float4*>(&X[(size_t)(base + r) * 128 + k]);
        ushort4 b;
        b.x = f2bf(v.x); b.y = f2bf(v.y); b.z = f2bf(v.z); b.w = f2bf(v.w);
        *reinterpret_cast<ushort4*>(lds + r * 256 + ((k * 2) ^ ((r & 15) << 4))) = b;
    }
    __syncthreads();
    const int w = t >> 6, l = t & 63, lr = l & 15, lg = l >> 4;
    const int rowbase = (w * 16 + lr) * 256, swz = lr << 4;
    bf16x8 afr[4];
    #pragma unroll
    for (int kk = 0; kk < 4; ++kk)
        afr[kk] = *reinterpret_cast<const bf16x8*>(lds + rowbase + ((kk * 64 + lg * 16) ^ swz));
    for (int ch = 0; ch < 3; ++ch) {
        const bf16x8* bf = reinterpret_cast<const bf16x8*>(frag + ch * 2048 * 8);
        f32x4 acc[8];
        #pragma unroll
        for (int n = 0; n < 8; ++n) acc[n] = (f32x4){0.f, 0.f, 0.f, 0.f};
        #pragma unroll
        for (int n = 0; n < 8; ++n)
            #pragma unroll
            for (int kk = 0; kk < 4; ++kk)
                acc[n] = __builtin_amdgcn_mfma_f32_16x16x32_bf16(afr[kk], bf[(n * 4 + kk) * 64 + l],
                                                                 acc[n], 0, 0, 0);
        u16* Y = (ch == 0) ? Y0 : (ch == 1) ? Y1 : Y2;
        #pragma unroll
        for (int n = 0; n < 8; ++n) {
            int col = n * 16 + lr;
            float bv = bias[ch * 128 + col];
            #pragma unroll
            for (int reg = 0; reg < 4; ++reg) {
                int r = base + w * 16 + lg * 4 + reg;
                if (r < R) Y[(size_t)r * 128 + col] = f2bf(acc[n][reg] + bv);
            }
        }
    }
}

// ---------- generic rows x 128 @ 128x128 MFMA GEMM, f32 out (hproj) ----------

__global__ __launch_bounds__(256) void gemm128(
    const float* __restrict__ X, const short* __restrict__ frag,
    const float* __restrict__ bias, float* __restrict__ Y, int R)
{
    __shared__ __align__(16) char lds[64 * 256];
    const int t = threadIdx.x;
    const int base = blockIdx.x * 64;
    for (int i = 0; i < 8; ++i) {
        int flat = i * 1024 + t * 4;
        int r = flat >> 7, k = flat & 127;
        float4 v = make_float4(0.f, 0.f, 0.f, 0.f);
        if (base + r < R) v = *reinterpret_cast<const float4*>(&X[(size_t)(base + r) * 128 + k]);
        ushort4 b;
        b.x = f2bf(v.x); b.y = f2bf(v.y); b.z = f2bf(v.z); b.w = f2bf(v.w);
        *reinterpret_cast<ushort4*>(lds + r * 256 + ((k * 2) ^ ((r & 15) << 4))) = b;
    }
    __syncthreads();
    const int w = t >> 6, l = t & 63, lr = l & 15, lg = l >> 4;
    const int rowbase = (w * 16 + lr) * 256, swz = lr << 4;
    bf16x8 afr[4];
    #pragma unroll
    for (int kk = 0; kk < 4; ++kk)
        afr[kk] = *reinterpret_cast<const bf16x8*>(lds + rowbase + ((kk * 64 + lg * 16) ^ swz));
    const bf16x8* bf = reinterpret_cast<const bf16x8*>(frag);
    f32x4 acc[8];
    #pragma unroll
    for (int n = 0; n < 8; ++n) acc[n] = (f32x4){0.f, 0.f, 0.f, 0.f};
    #pragma unroll
    for (int n = 0; n < 8; ++n)
        #pragma unroll
        for (int kk = 0; kk < 4; ++kk)
            acc[n] = __builtin_amdgcn_mfma_f32_16x16x32_bf16(afr[kk], bf[(n * 4 + kk) * 64 + l],
                                                             acc[n], 0, 0, 0);
    #pragma unroll
    for (int n = 0; n < 8; ++n) {
        int col = n * 16 + lr;
        float bv = bias[col];
        #pragma unroll
        for (int reg = 0; reg < 4; ++reg) {
            int r = base + w * 16 + lg * 4 + reg;
            if (r < R) Y[(size_t)r * 128 + col] = acc[n][reg] + bv;
        }
    }
}

// ---------- fused edge kernel (MFMA bf16, prefetched gathers, linear stores) ----------

__global__ __launch_bounds__(256, 4) void edge_mfma(
    const float* __restrict__ e, const int* __restrict__ src, const int* __restrict__ dst,
    const short* __restrict__ cfrag, const float* __restrict__ cbias,
    const short* __restrict__ efrag, const float* __restrict__ ebias,
    const u16* __restrict__ qbh, const u16* __restrict__ kbh,
    float* __restrict__ e_out, float* __restrict__ mean_out,
    float* __restrict__ logit, int E)
{
    __shared__ __align__(16) char lds[64 * 256];
    const int t = threadIdx.x;
    const int base = blockIdx.x * 64;

    // stage e tile as bf16, swizzled: byte ^= (row&15)<<4
    for (int i = 0; i < 8; ++i) {
        int flat = i * 1024 + t * 4;
        int r = flat >> 7, k = flat & 127;
        float4 v = make_float4(0.f, 0.f, 0.f, 0.f);
        if (base + r < E) v = *reinterpret_cast<const float4*>(&e[(size_t)(base + r) * 128 + k]);
        ushort4 b;
        b.x = f2bf(v.x); b.y = f2bf(v.y); b.z = f2bf(v.z); b.w = f2bf(v.w);
        *reinterpret_cast<ushort4*>(lds + r * 256 + ((k * 2) ^ ((r & 15) << 4))) = b;
    }

    const int w = t >> 6, l = t & 63;
    const int lr = l & 15, lg = l >> 4;
    const int rowbase = (w * 16 + lr) * 256;
    const int swz = lr << 4;

    // edge ids + indices (independent of LDS)
    int er[4], si[4], di[4];
    bool vld[4];
    #pragma unroll
    for (int reg = 0; reg < 4; ++reg) {
        int ei = base + w * 16 + lg * 4 + reg;
        vld[reg] = ei < E;
        int ce = vld[reg] ? ei : (E - 1);
        er[reg] = ei;
        si[reg] = src[ce];
        di[reg] = dst[ce];
    }
    // prefetch batch A (heads 0..3): latency hides under staging drain + barrier
    u16 kA[4][4], qA[4][4];
    #pragma unroll
    for (int n = 0; n < 4; ++n)
        #pragma unroll
        for (int reg = 0; reg < 4; ++reg) {
            kA[n][reg] = kbh[(size_t)si[reg] * 128 + n * 16 + lr];
            qA[n][reg] = qbh[(size_t)di[reg] * 128 + n * 16 + lr];
        }

    __syncthreads();

    bf16x8 afr[4];
    #pragma unroll
    for (int kk = 0; kk < 4; ++kk)
        afr[kk] = *reinterpret_cast<const bf16x8*>(lds + rowbase + ((kk * 64 + lg * 16) ^ swz));

    const bf16x8* cf = reinterpret_cast<const bf16x8*>(cfrag);
    f32x4 acc[8];
    #pragma unroll
    for (int n = 0; n < 8; ++n) acc[n] = (f32x4){0.f, 0.f, 0.f, 0.f};
    #pragma unroll
    for (int n = 0; n < 8; ++n)
        #pragma unroll
        for (int kk = 0; kk < 4; ++kk)
            acc[n] = __builtin_amdgcn_mfma_f32_16x16x32_bf16(afr[kk], cf[(n * 4 + kk) * 64 + l],
                                                             acc[n], 0, 0, 0);

    // prefetch batch B (heads 4..7): latency hides under epilogue A
    u16 kB[4][4], qB[4][4];
    #pragma unroll
    for (int n = 0; n < 4; ++n)
        #pragma unroll
        for (int reg = 0; reg < 4; ++reg) {
            kB[n][reg] = kbh[(size_t)si[reg] * 128 + (n + 4) * 16 + lr];
            qB[n][reg] = qbh[(size_t)di[reg] * 128 + (n + 4) * 16 + lr];
        }

    // epilogue: tanh -> score -> bf16 LDS; head-mean accum
    float macc[4] = {0.f, 0.f, 0.f, 0.f};
    #pragma unroll
    for (int n = 0; n < 8; ++n) {
        const int col = n * 16 + lr;
        const float cb = cbias[col];
        #pragma unroll
        for (int reg = 0; reg < 4; ++reg) {
            float kv = bf2f(n < 4 ? kA[n & 3][reg] : kB[n & 3][reg]);
            float qv = bf2f(n < 4 ? qA[n & 3][reg] : qB[n & 3][reg]);
            float sc = fast_tanh(acc[n][reg] + cb) * kv * qv;
            macc[reg] += sc;
            int row = w * 16 + lg * 4 + reg;
            *reinterpret_cast<u16*>(
                lds + row * 256 + ((col * 2) ^ ((row & 15) << 4))) = f2bf(sc);
        }
    }
    #pragma unroll
    for (int reg = 0; reg < 4; ++reg)
        if (vld[reg]) mean_out[(size_t)er[reg] * 16 + lr] = macc[reg] * 0.125f;

    // A-frags from score (in-wave LDS ordering)
    bf16x8 afr2[4];
    #pragma unroll
    for (int kk = 0; kk < 4; ++kk)
        afr2[kk] = *reinterpret_cast<const bf16x8*>(lds + rowbase + ((kk * 64 + lg * 16) ^ swz));

    // logit via indicator-MFMA: B[k][h] = (k>>4 == h); LINEAR store by edge id
    bf16x8 ind[4];
    #pragma unroll
    for (int kk = 0; kk < 4; ++kk)
        #pragma unroll
        for (int j = 0; j < 8; ++j)
            ind[kk][j] = ((kk * 32 + lg * 8 + j) >> 4 == lr) ? (short)0x3F80 : (short)0;
    f32x4 lac = (f32x4){0.f, 0.f, 0.f, 0.f};
    #pragma unroll
    for (int kk = 0; kk < 4; ++kk)
        lac = __builtin_amdgcn_mfma_f32_16x16x32_bf16(afr2[kk], ind[kk], lac, 0, 0, 0);
    if (lr < 8) {
        #pragma unroll
        for (int reg = 0; reg < 4; ++reg)
            if (vld[reg]) logit[(size_t)er[reg] * 8 + lr] = lac[reg] * ATTN_SCALE;
    }

    // GEMM2: e_out = score @ eproj_w.T
    const bf16x8* ef = reinterpret_cast<const bf16x8*>(efrag);
    f32x4 acc2[8];
    #pragma unroll
    for (int n = 0; n < 8; ++n) acc2[n] = (f32x4){0.f, 0.f, 0.f, 0.f};
    #pragma unroll
    for (int n = 0; n < 8; ++n)
        #pragma unroll
        for (int kk = 0; kk < 4; ++kk)
            acc2[n] = __builtin_amdgcn_mfma_f32_16x16x32_bf16(afr2[kk], ef[(n * 4 + kk) * 64 + l],
                                                              acc2[n], 0, 0, 0);

    // e_out roundtrip: bf16 -> LDS -> coalesced float4 stores
    #pragma unroll
    for (int n = 0; n < 8; ++n) {
        const int col = n * 16 + lr;
        const float eb = ebias[col];
        #pragma unroll
        for (int reg = 0; reg < 4; ++reg) {
            int row = w * 16 + lg * 4 + reg;
            *reinterpret_cast<u16*>(
                lds + row * 256 + ((col * 2) ^ ((row & 15) << 4))) = f2bf(acc2[n][reg] + eb);
        }
    }
    #pragma unroll
    for (int rh = 0; rh < 2; ++rh) {
        #pragma unroll
        for (int ih = 0; ih < 2; ++ih) {
            int row = w * 16 + (l >> 3) + 8 * rh;
            int col = (l & 7) * 8 + 64 * ih;
            bf16x8 sv = *reinterpret_cast<const bf16x8*>(
                lds + row * 256 + ((col * 2) ^ ((row & 15) << 4)));
            float4 o0, o1;
            o0.x = bf2f((u16)sv[0]); o0.y = bf2f((u16)sv[1]);
            o0.z = bf2f((u16)sv[2]); o0.w = bf2f((u16)sv[3]);
            o1.x = bf2f((u16)sv[4]); o1.y = bf2f((u16)sv[5]);
            o1.z = bf2f((u16)sv[6]); o1.w = bf2f((u16)sv[7]);
            if (base + row < E) {
                *reinterpret_cast<float4*>(&e_out[(size_t)(base + row) * 128 + col]) = o0;
                *reinterpret_cast<float4*>(&e_out[(size_t)(base + row) * 128 + col + 4]) = o1;
            }
        }
    }
}

// ---------- per-node softmax + aggregation ----------

__global__ __launch_bounds__(256) void node_kernel(
    const int* __restrict__ offsets, const int* __restrict__ eidx,
    const int* __restrict__ src, const float* __restrict__ logit,
    const u16* __restrict__ vbh, float* __restrict__ hagg, int N)
{
    __shared__ int   ls_src[4][64];
    __shared__ float ls_l[4][64][8];
    const int t = threadIdx.x, w = t >> 6, lane = t & 63;
    const int node = blockIdx.x * 4 + w;
    int off = 0, deg = 0;
    if (node < N) { off = offsets[node]; deg = offsets[node + 1] - off; }

    const int h = lane & 7, g = lane >> 3;
    float m = -3.0e38f, s = 0.f;

    for (int c0 = 0; c0 < deg; c0 += 64) {
        int cnt = min(64, deg - c0);
        if (lane < cnt) {
            int eid = eidx[off + c0 + lane];
            ls_src[w][lane] = src[eid];
            float4 l0 = *reinterpret_cast<const float4*>(&logit[(size_t)eid * 8]);
            float4 l1 = *reinterpret_cast<const float4*>(&logit[(size_t)eid * 8 + 4]);
            *reinterpret_cast<float4*>(&ls_l[w][lane][0]) = l0;
            *reinterpret_cast<float4*>(&ls_l[w][lane][4]) = l1;
        }
        __asm__ __volatile__("s_waitcnt lgkmcnt(0)" ::: "memory");
        float cm = -3.0e38f;
        for (int j = g; j < cnt; j += 8) cm = fmaxf(cm, ls_l[w][j][h]);
        cm = fmaxf(cm, __shfl_xor(cm, 8));
        cm = fmaxf(cm, __shfl_xor(cm, 16));
        cm = fmaxf(cm, __shfl_xor(cm, 32));
        float mn = fmaxf(m, cm);
        float cs = 0.f;
        for (int j = g; j < cnt; j += 8) cs += __expf(ls_l[w][j][h] - mn);
        cs += __shfl_xor(cs, 8); cs += __shfl_xor(cs, 16); cs += __shfl_xor(cs, 32);
        s = s * __expf(m - mn) + cs;
        m = mn;
    }
    float inv = (deg > 0) ? 1.f / s : 0.f;

    float a0 = 0.f, a1 = 0.f;
    const int d0 = lane, d1 = lane + 64, h0 = lane >> 4, h1 = 4 + h0;
    for (int c0 = 0; c0 < deg; c0 += 64) {
        int cnt = min(64, deg - c0);
        if (deg > 64 && lane < cnt) {
            int eid = eidx[off + c0 + lane];
            ls_src[w][lane] = src[eid];
            float4 l0 = *reinterpret_cast<const float4*>(&logit[(size_t)eid * 8]);
            float4 l1 = *reinterpret_cast<const float4*>(&logit[(size_t)eid * 8 + 4]);
            *reinterpret_cast<float4*>(&ls_l[w][lane][0]) = l0;
            *reinterpret_cast<float4*>(&ls_l[w][lane][4]) = l1;
        }
        __asm__ __volatile__("s_waitcnt lgkmcnt(0)" ::: "memory");
        for (int j = g; j < cnt; j += 8)
            ls_l[w][j][h] = __expf(ls_l[w][j][h] - m) * inv;
        __asm__ __volatile__("s_waitcnt lgkmcnt(0)" ::: "memory");
        #pragma unroll 4
        for (int j = 0; j < cnt; ++j) {
            int sn = ls_src[w][j];
            float w0 = ls_l[w][j][h0], w1 = ls_l[w][j][h1];
            a0 += w0 * bf2f(vbh[(size_t)sn * 128 + d0]);
            a1 += w1 * bf2f(vbh[(size_t)sn * 128 + d1]);
        }
    }
    if (node < N) {
        hagg[(size_t)node * 128 + d0] = a0;
        hagg[(size_t)node * 128 + d1] = a1;
    }
}

// ---------- launcher ----------

extern "C" void kernel_launch(void* const* d_in, const int* in_sizes, int n_in,
                              void* d_out, int out_size, void* d_ws, size_t ws_size,
                              hipStream_t stream)
{
    const float* h       = (const float*)d_in[0];
    const float* e       = (const float*)d_in[1];
    const int*   src     = (const int*)d_in[2];
    const int*   dst     = (const int*)d_in[3];
    const float* qkv_w   = (const float*)d_in[4];
    const float* qkv_b   = (const float*)d_in[5];
    const float* c_w     = (const float*)d_in[6];
    const float* c_b     = (const float*)d_in[7];
    const float* hproj_w = (const float*)d_in[8];
    const float* hproj_b = (const float*)d_in[9];
    const float* eproj_w = (const float*)d_in[10];
    const float* eproj_b = (const float*)d_in[11];

    const int N = in_sizes[0] / 128;
    const int E = in_sizes[1] / 128;

    float* h_out    = (float*)d_out;
    float* e_out    = h_out + (size_t)N * 128;
    float* mean_out = e_out + (size_t)E * 128;

    char* wp = (char*)d_ws;
    auto alloc = [&](size_t b) {
        void* p = (void*)wp;
        wp += (b + 255) & ~(size_t)255;
        return p;
    };
    short* qkvfrag = (short*)alloc(sizeof(short) * 3 * 2048 * 8);
    short* cfragb  = (short*)alloc(sizeof(short) * 2048 * 8);
    short* efragb  = (short*)alloc(sizeof(short) * 2048 * 8);
    short* hpfrag  = (short*)alloc(sizeof(short) * 2048 * 8);
    u16*   qbh     = (u16*)alloc(sizeof(u16) * (size_t)N * 128);
    u16*   kbh     = (u16*)alloc(sizeof(u16) * (size_t)N * 128);
    u16*   vbh     = (u16*)alloc(sizeof(u16) * (size_t)N * 128);
    float* hagg    = (float*)alloc(sizeof(float) * (size_t)N * 128);
    float* logit   = (float*)alloc(sizeof(float) * (size_t)E * 8);
    int*   counts  = (int*)alloc(sizeof(int) * (N + 1));
    int*   offs    = (int*)alloc(sizeof(int) * (N + 1));
    int*   cursor  = (int*)alloc(sizeof(int) * (N + 1));
    int*   stmp    = (int*)alloc(sizeof(int) * (N + 1));
    int*   bsum    = (int*)alloc(sizeof(int) * 64);
    int*   eidx    = (int*)alloc(sizeof(int) * E);

    hipMemsetAsync(counts, 0, sizeof(int) * (N + 1), stream);

    make_frag<<<8, 256, 0, stream>>>(qkv_w, qkvfrag);
    make_frag<<<8, 256, 0, stream>>>(qkv_w + 128 * 128, qkvfrag + 2048 * 8);
    make_frag<<<8, 256, 0, stream>>>(qkv_w + 2 * 128 * 128, qkvfrag + 2 * 2048 * 8);
    make_frag<<<8, 256, 0, stream>>>(c_w, cfragb);
    make_frag<<<8, 256, 0, stream>>>(eproj_w, efragb);
    make_frag<<<8, 256, 0, stream>>>(hproj_w, hpfrag);

    qkv_gemm<<<(N + 63) / 64, 256, 0, stream>>>(h, qkvfrag, qkv_b, qbh, kbh, vbh, N);

    hist_kernel<<<(E + 255) / 256, 256, 0, stream>>>(dst, counts, E);
    int nb = (N + 1023) / 1024;
    scan1<<<nb, 256, 0, stream>>>(counts, stmp, bsum, N);
    scan2<<<1, 64, 0, stream>>>(bsum, nb);
    scan3<<<(N + 255) / 256, 256, 0, stream>>>(stmp, bsum, offs, N);
    copy_kernel<<<(N + 256) / 256, 256, 0, stream>>>(offs, cursor, N + 1);
    scatter_kernel<<<(E + 255) / 256, 256, 0, stream>>>(dst, cursor, eidx, E);

    edge_mfma<<<(E + 63) / 64, 256, 0, stream>>>(e, src, dst, cfragb, c_b, efragb,
                                                 eproj_b, qbh, kbh, e_out, mean_out, logit, E);

    node_kernel<<<(N + 3) / 4, 256, 0, stream>>>(offs, eidx, src, logit, vbh, hagg, N);

    gemm128<<<(N + 63) / 64, 256, 0, stream>>>(hagg, hpfrag, hproj_b, h_out, N);
}

// Round 6
// 498.506 us; speedup vs baseline: 1.2914x; 1.1215x over previous
//
#include <hip/hip_runtime.h>
#include <cmath>

typedef __attribute__((ext_vector_type(8))) short bf16x8;
typedef __attribute__((ext_vector_type(4))) float f32x4;
typedef unsigned short u16;

#define ATTN_SCALE 0.25f

__device__ inline u16 f2bf(float x) {
    union { float f; unsigned u; } v; v.f = x;
    unsigned r = v.u + 0x7FFFu + ((v.u >> 16) & 1u);
    return (u16)(r >> 16);
}
__device__ inline float bf2f(u16 u) {
    union { unsigned u; float f; } v; v.u = ((unsigned)u) << 16; return v.f;
}
__device__ inline float fast_tanh(float x) {
    float xc = fminf(fmaxf(x, -15.f), 15.f);
    float t = __expf(2.f * xc);
    return (t - 1.f) * __builtin_amdgcn_rcpf(t + 1.f);
}

// ---------- CSR build ----------

__global__ __launch_bounds__(256) void hist_kernel(const int* __restrict__ dst,
                                                   int* __restrict__ counts, int E) {
    int i = blockIdx.x * 256 + threadIdx.x;
    if (i < E) atomicAdd(&counts[dst[i]], 1);
}

__global__ __launch_bounds__(256) void scan1(const int* __restrict__ counts,
                                             int* __restrict__ tmp, int* __restrict__ bsum, int N) {
    __shared__ int wsum[4];
    int b = blockIdx.x, t = threadIdx.x;
    int base = b * 1024 + t * 4;
    int v0 = (base + 0 < N) ? counts[base + 0] : 0;
    int v1 = (base + 1 < N) ? counts[base + 1] : 0;
    int v2 = (base + 2 < N) ? counts[base + 2] : 0;
    int v3 = (base + 3 < N) ? counts[base + 3] : 0;
    int p0 = v0, p1 = p0 + v1, p2 = p1 + v2, p3 = p2 + v3;
    int s = p3;
    int lane = t & 63, wid = t >> 6;
    int sc = s;
    #pragma unroll
    for (int d = 1; d < 64; d <<= 1) {
        int o = __shfl_up(sc, d);
        if (lane >= d) sc += o;
    }
    if (lane == 63) wsum[wid] = sc;
    __syncthreads();
    int wof = 0;
    #pragma unroll
    for (int i = 0; i < 4; ++i) if (i < wid) wof += wsum[i];
    int excl = wof + sc - s;
    if (base + 0 < N) tmp[base + 0] = excl + p0;
    if (base + 1 < N) tmp[base + 1] = excl + p1;
    if (base + 2 < N) tmp[base + 2] = excl + p2;
    if (base + 3 < N) tmp[base + 3] = excl + p3;
    if (t == 255) bsum[b] = wof + sc;
}

__global__ void scan2(int* __restrict__ bsum, int nb) {
    int t = threadIdx.x;
    int v = (t < nb) ? bsum[t] : 0;
    int sc = v;
    #pragma unroll
    for (int d = 1; d < 64; d <<= 1) {
        int o = __shfl_up(sc, d);
        if (t >= d) sc += o;
    }
    if (t < nb) bsum[t] = sc - v;
}

__global__ __launch_bounds__(256) void scan3(const int* __restrict__ tmp,
                                             const int* __restrict__ bsum,
                                             int* __restrict__ offsets, int N) {
    int i = blockIdx.x * 256 + threadIdx.x;
    if (i < N) offsets[i + 1] = tmp[i] + bsum[i >> 10];
    if (i == 0) offsets[0] = 0;
}

__global__ __launch_bounds__(256) void copy_kernel(const int* __restrict__ a,
                                                   int* __restrict__ b, int n) {
    int i = blockIdx.x * 256 + threadIdx.x;
    if (i < n) b[i] = a[i];
}

__global__ __launch_bounds__(256) void scatter_kernel(const int* __restrict__ dst,
                                                      int* __restrict__ cursor,
                                                      int* __restrict__ eidx, int E) {
    int i = blockIdx.x * 256 + threadIdx.x;
    if (i < E) {
        int p = atomicAdd(&cursor[dst[i]], 1);
        eidx[p] = i;
    }
}

// ---------- weight -> MFMA B-fragment (bf16, frag-linear) ----------
__global__ __launch_bounds__(256) void make_frag(const float* __restrict__ W,
                                                 short* __restrict__ out) {
    int id = blockIdx.x * 256 + threadIdx.x;
    if (id >= 2048) return;
    int l = id & 63, t16 = id >> 6;
    int kk = t16 & 3, n = t16 >> 2;
    int col = n * 16 + (l & 15);
    int k0 = kk * 32 + (l >> 4) * 8;
    #pragma unroll
    for (int j = 0; j < 8; ++j)
        out[id * 8 + j] = (short)f2bf(W[col * 128 + k0 + j]);
}

// ---------- qkv GEMM: 3 channels, bf16 outputs ----------

__global__ __launch_bounds__(256) void qkv_gemm(
    const float* __restrict__ X, const short* __restrict__ frag,
    const float* __restrict__ bias,
    u16* __restrict__ Y0, u16* __restrict__ Y1, u16* __restrict__ Y2, int R)
{
    __shared__ __align__(16) char lds[64 * 256];
    const int t = threadIdx.x;
    const int base = blockIdx.x * 64;
    for (int i = 0; i < 8; ++i) {
        int flat = i * 1024 + t * 4;
        int r = flat >> 7, k = flat & 127;
        float4 v = make_float4(0.f, 0.f, 0.f, 0.f);
        if (base + r < R) v = *reinterpret_cast<const float4*>(&X[(size_t)(base + r) * 128 + k]);
        ushort4 b;
        b.x = f2bf(v.x); b.y = f2bf(v.y); b.z = f2bf(v.z); b.w = f2bf(v.w);
        *reinterpret_cast<ushort4*>(lds + r * 256 + ((k * 2) ^ ((r & 15) << 4))) = b;
    }
    __syncthreads();
    const int w = t >> 6, l = t & 63, lr = l & 15, lg = l >> 4;
    const int rowbase = (w * 16 + lr) * 256, swz = lr << 4;
    bf16x8 afr[4];
    #pragma unroll
    for (int kk = 0; kk < 4; ++kk)
        afr[kk] = *reinterpret_cast<const bf16x8*>(lds + rowbase + ((kk * 64 + lg * 16) ^ swz));
    for (int ch = 0; ch < 3; ++ch) {
        const bf16x8* bf = reinterpret_cast<const bf16x8*>(frag + ch * 2048 * 8);
        f32x4 acc[8];
        #pragma unroll
        for (int n = 0; n < 8; ++n) acc[n] = (f32x4){0.f, 0.f, 0.f, 0.f};
        #pragma unroll
        for (int n = 0; n < 8; ++n)
            #pragma unroll
            for (int kk = 0; kk < 4; ++kk)
                acc[n] = __builtin_amdgcn_mfma_f32_16x16x32_bf16(afr[kk], bf[(n * 4 + kk) * 64 + l],
                                                                 acc[n], 0, 0, 0);
        u16* Y = (ch == 0) ? Y0 : (ch == 1) ? Y1 : Y2;
        #pragma unroll
        for (int n = 0; n < 8; ++n) {
            int col = n * 16 + lr;
            float bv = bias[ch * 128 + col];
            #pragma unroll
            for (int reg = 0; reg < 4; ++reg) {
                int r = base + w * 16 + lg * 4 + reg;
                if (r < R) Y[(size_t)r * 128 + col] = f2bf(acc[n][reg] + bv);
            }
        }
    }
}

// ---------- generic rows x 128 @ 128x128 MFMA GEMM, f32 out (hproj) ----------

__global__ __launch_bounds__(256) void gemm128(
    const float* __restrict__ X, const short* __restrict__ frag,
    const float* __restrict__ bias, float* __restrict__ Y, int R)
{
    __shared__ __align__(16) char lds[64 * 256];
    const int t = threadIdx.x;
    const int base = blockIdx.x * 64;
    for (int i = 0; i < 8; ++i) {
        int flat = i * 1024 + t * 4;
        int r = flat >> 7, k = flat & 127;
        float4 v = make_float4(0.f, 0.f, 0.f, 0.f);
        if (base + r < R) v = *reinterpret_cast<const float4*>(&X[(size_t)(base + r) * 128 + k]);
        ushort4 b;
        b.x = f2bf(v.x); b.y = f2bf(v.y); b.z = f2bf(v.z); b.w = f2bf(v.w);
        *reinterpret_cast<ushort4*>(lds + r * 256 + ((k * 2) ^ ((r & 15) << 4))) = b;
    }
    __syncthreads();
    const int w = t >> 6, l = t & 63, lr = l & 15, lg = l >> 4;
    const int rowbase = (w * 16 + lr) * 256, swz = lr << 4;
    bf16x8 afr[4];
    #pragma unroll
    for (int kk = 0; kk < 4; ++kk)
        afr[kk] = *reinterpret_cast<const bf16x8*>(lds + rowbase + ((kk * 64 + lg * 16) ^ swz));
    const bf16x8* bf = reinterpret_cast<const bf16x8*>(frag);
    f32x4 acc[8];
    #pragma unroll
    for (int n = 0; n < 8; ++n) acc[n] = (f32x4){0.f, 0.f, 0.f, 0.f};
    #pragma unroll
    for (int n = 0; n < 8; ++n)
        #pragma unroll
        for (int kk = 0; kk < 4; ++kk)
            acc[n] = __builtin_amdgcn_mfma_f32_16x16x32_bf16(afr[kk], bf[(n * 4 + kk) * 64 + l],
                                                             acc[n], 0, 0, 0);
    #pragma unroll
    for (int n = 0; n < 8; ++n) {
        int col = n * 16 + lr;
        float bv = bias[col];
        #pragma unroll
        for (int reg = 0; reg < 4; ++reg) {
            int r = base + w * 16 + lg * 4 + reg;
            if (r < R) Y[(size_t)r * 128 + col] = acc[n][reg] + bv;
        }
    }
}

// ---------- fused edge kernel (MFMA bf16, prefetched gathers, no reg cap) ----------
// NOTE: no min-waves clamp — __launch_bounds__(256,4) capped VGPR at 128 and
// caused scratch spills (+337 MB HBM writes, R4/R5 forensics). Let the
// compiler pick VGPR; prefetch batches hide gather latency instead.

__global__ __launch_bounds__(256) void edge_mfma(
    const float* __restrict__ e, const int* __restrict__ src, const int* __restrict__ dst,
    const short* __restrict__ cfrag, const float* __restrict__ cbias,
    const short* __restrict__ efrag, const float* __restrict__ ebias,
    const u16* __restrict__ qbh, const u16* __restrict__ kbh,
    float* __restrict__ e_out, float* __restrict__ mean_out,
    float* __restrict__ logit, int E)
{
    __shared__ __align__(16) char lds[64 * 256];
    const int t = threadIdx.x;
    const int base = blockIdx.x * 64;

    // stage e tile as bf16, swizzled: byte ^= (row&15)<<4
    for (int i = 0; i < 8; ++i) {
        int flat = i * 1024 + t * 4;
        int r = flat >> 7, k = flat & 127;
        float4 v = make_float4(0.f, 0.f, 0.f, 0.f);
        if (base + r < E) v = *reinterpret_cast<const float4*>(&e[(size_t)(base + r) * 128 + k]);
        ushort4 b;
        b.x = f2bf(v.x); b.y = f2bf(v.y); b.z = f2bf(v.z); b.w = f2bf(v.w);
        *reinterpret_cast<ushort4*>(lds + r * 256 + ((k * 2) ^ ((r & 15) << 4))) = b;
    }

    const int w = t >> 6, l = t & 63;
    const int lr = l & 15, lg = l >> 4;
    const int rowbase = (w * 16 + lr) * 256;
    const int swz = lr << 4;

    // edge ids + indices (independent of LDS)
    int er[4], si[4], di[4];
    bool vld[4];
    #pragma unroll
    for (int reg = 0; reg < 4; ++reg) {
        int ei = base + w * 16 + lg * 4 + reg;
        vld[reg] = ei < E;
        int ce = vld[reg] ? ei : (E - 1);
        er[reg] = ei;
        si[reg] = src[ce];
        di[reg] = dst[ce];
    }
    // prefetch batch A (heads 0..3): latency hides under staging drain + barrier
    u16 kA[4][4], qA[4][4];
    #pragma unroll
    for (int n = 0; n < 4; ++n)
        #pragma unroll
        for (int reg = 0; reg < 4; ++reg) {
            kA[n][reg] = kbh[(size_t)si[reg] * 128 + n * 16 + lr];
            qA[n][reg] = qbh[(size_t)di[reg] * 128 + n * 16 + lr];
        }

    __syncthreads();

    bf16x8 afr[4];
    #pragma unroll
    for (int kk = 0; kk < 4; ++kk)
        afr[kk] = *reinterpret_cast<const bf16x8*>(lds + rowbase + ((kk * 64 + lg * 16) ^ swz));

    const bf16x8* cf = reinterpret_cast<const bf16x8*>(cfrag);
    f32x4 acc[8];
    #pragma unroll
    for (int n = 0; n < 8; ++n) acc[n] = (f32x4){0.f, 0.f, 0.f, 0.f};
    #pragma unroll
    for (int n = 0; n < 8; ++n)
        #pragma unroll
        for (int kk = 0; kk < 4; ++kk)
            acc[n] = __builtin_amdgcn_mfma_f32_16x16x32_bf16(afr[kk], cf[(n * 4 + kk) * 64 + l],
                                                             acc[n], 0, 0, 0);

    // prefetch batch B (heads 4..7): latency hides under epilogue A
    u16 kB[4][4], qB[4][4];
    #pragma unroll
    for (int n = 0; n < 4; ++n)
        #pragma unroll
        for (int reg = 0; reg < 4; ++reg) {
            kB[n][reg] = kbh[(size_t)si[reg] * 128 + (n + 4) * 16 + lr];
            qB[n][reg] = qbh[(size_t)di[reg] * 128 + (n + 4) * 16 + lr];
        }

    // epilogue: tanh -> score -> bf16 LDS; head-mean accum
    float macc[4] = {0.f, 0.f, 0.f, 0.f};
    #pragma unroll
    for (int n = 0; n < 8; ++n) {
        const int col = n * 16 + lr;
        const float cb = cbias[col];
        #pragma unroll
        for (int reg = 0; reg < 4; ++reg) {
            float kv = bf2f(n < 4 ? kA[n & 3][reg] : kB[n & 3][reg]);
            float qv = bf2f(n < 4 ? qA[n & 3][reg] : qB[n & 3][reg]);
            float sc = fast_tanh(acc[n][reg] + cb) * kv * qv;
            macc[reg] += sc;
            int row = w * 16 + lg * 4 + reg;
            *reinterpret_cast<u16*>(
                lds + row * 256 + ((col * 2) ^ ((row & 15) << 4))) = f2bf(sc);
        }
    }
    #pragma unroll
    for (int reg = 0; reg < 4; ++reg)
        if (vld[reg]) mean_out[(size_t)er[reg] * 16 + lr] = macc[reg] * 0.125f;

    // A-frags from score (in-wave LDS ordering)
    bf16x8 afr2[4];
    #pragma unroll
    for (int kk = 0; kk < 4; ++kk)
        afr2[kk] = *reinterpret_cast<const bf16x8*>(lds + rowbase + ((kk * 64 + lg * 16) ^ swz));

    // logit via indicator-MFMA: B[k][h] = (k>>4 == h); LINEAR store by edge id
    bf16x8 ind[4];
    #pragma unroll
    for (int kk = 0; kk < 4; ++kk)
        #pragma unroll
        for (int j = 0; j < 8; ++j)
            ind[kk][j] = ((kk * 32 + lg * 8 + j) >> 4 == lr) ? (short)0x3F80 : (short)0;
    f32x4 lac = (f32x4){0.f, 0.f, 0.f, 0.f};
    #pragma unroll
    for (int kk = 0; kk < 4; ++kk)
        lac = __builtin_amdgcn_mfma_f32_16x16x32_bf16(afr2[kk], ind[kk], lac, 0, 0, 0);
    if (lr < 8) {
        #pragma unroll
        for (int reg = 0; reg < 4; ++reg)
            if (vld[reg]) logit[(size_t)er[reg] * 8 + lr] = lac[reg] * ATTN_SCALE;
    }

    // GEMM2: e_out = score @ eproj_w.T
    const bf16x8* ef = reinterpret_cast<const bf16x8*>(efrag);
    f32x4 acc2[8];
    #pragma unroll
    for (int n = 0; n < 8; ++n) acc2[n] = (f32x4){0.f, 0.f, 0.f, 0.f};
    #pragma unroll
    for (int n = 0; n < 8; ++n)
        #pragma unroll
        for (int kk = 0; kk < 4; ++kk)
            acc2[n] = __builtin_amdgcn_mfma_f32_16x16x32_bf16(afr2[kk], ef[(n * 4 + kk) * 64 + l],
                                                              acc2[n], 0, 0, 0);

    // e_out roundtrip: bf16 -> LDS -> coalesced float4 stores
    #pragma unroll
    for (int n = 0; n < 8; ++n) {
        const int col = n * 16 + lr;
        const float eb = ebias[col];
        #pragma unroll
        for (int reg = 0; reg < 4; ++reg) {
            int row = w * 16 + lg * 4 + reg;
            *reinterpret_cast<u16*>(
                lds + row * 256 + ((col * 2) ^ ((row & 15) << 4))) = f2bf(acc2[n][reg] + eb);
        }
    }
    #pragma unroll
    for (int rh = 0; rh < 2; ++rh) {
        #pragma unroll
        for (int ih = 0; ih < 2; ++ih) {
            int row = w * 16 + (l >> 3) + 8 * rh;
            int col = (l & 7) * 8 + 64 * ih;
            bf16x8 sv = *reinterpret_cast<const bf16x8*>(
                lds + row * 256 + ((col * 2) ^ ((row & 15) << 4)));
            float4 o0, o1;
            o0.x = bf2f((u16)sv[0]); o0.y = bf2f((u16)sv[1]);
            o0.z = bf2f((u16)sv[2]); o0.w = bf2f((u16)sv[3]);
            o1.x = bf2f((u16)sv[4]); o1.y = bf2f((u16)sv[5]);
            o1.z = bf2f((u16)sv[6]); o1.w = bf2f((u16)sv[7]);
            if (base + row < E) {
                *reinterpret_cast<float4*>(&e_out[(size_t)(base + row) * 128 + col]) = o0;
                *reinterpret_cast<float4*>(&e_out[(size_t)(base + row) * 128 + col + 4]) = o1;
            }
        }
    }
}

// ---------- per-node softmax + aggregation ----------

__global__ __launch_bounds__(256) void node_kernel(
    const int* __restrict__ offsets, const int* __restrict__ eidx,
    const int* __restrict__ src, const float* __restrict__ logit,
    const u16* __restrict__ vbh, float* __restrict__ hagg, int N)
{
    __shared__ int   ls_src[4][64];
    __shared__ float ls_l[4][64][8];
    const int t = threadIdx.x, w = t >> 6, lane = t & 63;
    const int node = blockIdx.x * 4 + w;
    int off = 0, deg = 0;
    if (node < N) { off = offsets[node]; deg = offsets[node + 1] - off; }

    const int h = lane & 7, g = lane >> 3;
    float m = -3.0e38f, s = 0.f;

    for (int c0 = 0; c0 < deg; c0 += 64) {
        int cnt = min(64, deg - c0);
        if (lane < cnt) {
            int eid = eidx[off + c0 + lane];
            ls_src[w][lane] = src[eid];
            float4 l0 = *reinterpret_cast<const float4*>(&logit[(size_t)eid * 8]);
            float4 l1 = *reinterpret_cast<const float4*>(&logit[(size_t)eid * 8 + 4]);
            *reinterpret_cast<float4*>(&ls_l[w][lane][0]) = l0;
            *reinterpret_cast<float4*>(&ls_l[w][lane][4]) = l1;
        }
        __asm__ __volatile__("s_waitcnt lgkmcnt(0)" ::: "memory");
        float cm = -3.0e38f;
        for (int j = g; j < cnt; j += 8) cm = fmaxf(cm, ls_l[w][j][h]);
        cm = fmaxf(cm, __shfl_xor(cm, 8));
        cm = fmaxf(cm, __shfl_xor(cm, 16));
        cm = fmaxf(cm, __shfl_xor(cm, 32));
        float mn = fmaxf(m, cm);
        float cs = 0.f;
        for (int j = g; j < cnt; j += 8) cs += __expf(ls_l[w][j][h] - mn);
        cs += __shfl_xor(cs, 8); cs += __shfl_xor(cs, 16); cs += __shfl_xor(cs, 32);
        s = s * __expf(m - mn) + cs;
        m = mn;
    }
    float inv = (deg > 0) ? 1.f / s : 0.f;

    float a0 = 0.f, a1 = 0.f;
    const int d0 = lane, d1 = lane + 64, h0 = lane >> 4, h1 = 4 + h0;
    for (int c0 = 0; c0 < deg; c0 += 64) {
        int cnt = min(64, deg - c0);
        if (deg > 64 && lane < cnt) {
            int eid = eidx[off + c0 + lane];
            ls_src[w][lane] = src[eid];
            float4 l0 = *reinterpret_cast<const float4*>(&logit[(size_t)eid * 8]);
            float4 l1 = *reinterpret_cast<const float4*>(&logit[(size_t)eid * 8 + 4]);
            *reinterpret_cast<float4*>(&ls_l[w][lane][0]) = l0;
            *reinterpret_cast<float4*>(&ls_l[w][lane][4]) = l1;
        }
        __asm__ __volatile__("s_waitcnt lgkmcnt(0)" ::: "memory");
        for (int j = g; j < cnt; j += 8)
            ls_l[w][j][h] = __expf(ls_l[w][j][h] - m) * inv;
        __asm__ __volatile__("s_waitcnt lgkmcnt(0)" ::: "memory");
        #pragma unroll 4
        for (int j = 0; j < cnt; ++j) {
            int sn = ls_src[w][j];
            float w0 = ls_l[w][j][h0], w1 = ls_l[w][j][h1];
            a0 += w0 * bf2f(vbh[(size_t)sn * 128 + d0]);
            a1 += w1 * bf2f(vbh[(size_t)sn * 128 + d1]);
        }
    }
    if (node < N) {
        hagg[(size_t)node * 128 + d0] = a0;
        hagg[(size_t)node * 128 + d1] = a1;
    }
}

// ---------- launcher ----------

extern "C" void kernel_launch(void* const* d_in, const int* in_sizes, int n_in,
                              void* d_out, int out_size, void* d_ws, size_t ws_size,
                              hipStream_t stream)
{
    const float* h       = (const float*)d_in[0];
    const float* e       = (const float*)d_in[1];
    const int*   src     = (const int*)d_in[2];
    const int*   dst     = (const int*)d_in[3];
    const float* qkv_w   = (const float*)d_in[4];
    const float* qkv_b   = (const float*)d_in[5];
    const float* c_w     = (const float*)d_in[6];
    const float* c_b     = (const float*)d_in[7];
    const float* hproj_w = (const float*)d_in[8];
    const float* hproj_b = (const float*)d_in[9];
    const float* eproj_w = (const float*)d_in[10];
    const float* eproj_b = (const float*)d_in[11];

    const int N = in_sizes[0] / 128;
    const int E = in_sizes[1] / 128;

    float* h_out    = (float*)d_out;
    float* e_out    = h_out + (size_t)N * 128;
    float* mean_out = e_out + (size_t)E * 128;

    char* wp = (char*)d_ws;
    auto alloc = [&](size_t b) {
        void* p = (void*)wp;
        wp += (b + 255) & ~(size_t)255;
        return p;
    };
    short* qkvfrag = (short*)alloc(sizeof(short) * 3 * 2048 * 8);
    short* cfragb  = (short*)alloc(sizeof(short) * 2048 * 8);
    short* efragb  = (short*)alloc(sizeof(short) * 2048 * 8);
    short* hpfrag  = (short*)alloc(sizeof(short) * 2048 * 8);
    u16*   qbh     = (u16*)alloc(sizeof(u16) * (size_t)N * 128);
    u16*   kbh     = (u16*)alloc(sizeof(u16) * (size_t)N * 128);
    u16*   vbh     = (u16*)alloc(sizeof(u16) * (size_t)N * 128);
    float* hagg    = (float*)alloc(sizeof(float) * (size_t)N * 128);
    float* logit   = (float*)alloc(sizeof(float) * (size_t)E * 8);
    int*   counts  = (int*)alloc(sizeof(int) * (N + 1));
    int*   offs    = (int*)alloc(sizeof(int) * (N + 1));
    int*   cursor  = (int*)alloc(sizeof(int) * (N + 1));
    int*   stmp    = (int*)alloc(sizeof(int) * (N + 1));
    int*   bsum    = (int*)alloc(sizeof(int) * 64);
    int*   eidx    = (int*)alloc(sizeof(int) * E);

    hipMemsetAsync(counts, 0, sizeof(int) * (N + 1), stream);

    make_frag<<<8, 256, 0, stream>>>(qkv_w, qkvfrag);
    make_frag<<<8, 256, 0, stream>>>(qkv_w + 128 * 128, qkvfrag + 2048 * 8);
    make_frag<<<8, 256, 0, stream>>>(qkv_w + 2 * 128 * 128, qkvfrag + 2 * 2048 * 8);
    make_frag<<<8, 256, 0, stream>>>(c_w, cfragb);
    make_frag<<<8, 256, 0, stream>>>(eproj_w, efragb);
    make_frag<<<8, 256, 0, stream>>>(hproj_w, hpfrag);

    qkv_gemm<<<(N + 63) / 64, 256, 0, stream>>>(h, qkvfrag, qkv_b, qbh, kbh, vbh, N);

    hist_kernel<<<(E + 255) / 256, 256, 0, stream>>>(dst, counts, E);
    int nb = (N + 1023) / 1024;
    scan1<<<nb, 256, 0, stream>>>(counts, stmp, bsum, N);
    scan2<<<1, 64, 0, stream>>>(bsum, nb);
    scan3<<<(N + 255) / 256, 256, 0, stream>>>(stmp, bsum, offs, N);
    copy_kernel<<<(N + 256) / 256, 256, 0, stream>>>(offs, cursor, N + 1);
    scatter_kernel<<<(E + 255) / 256, 256, 0, stream>>>(dst, cursor, eidx, E);

    edge_mfma<<<(E + 63) / 64, 256, 0, stream>>>(e, src, dst, cfragb, c_b, efragb,
                                                 eproj_b, qbh, kbh, e_out, mean_out, logit, E);

    node_kernel<<<(N + 3) / 4, 256, 0, stream>>>(offs, eidx, src, logit, vbh, hagg, N);

    gemm128<<<(N + 63) / 64, 256, 0, stream>>>(hagg, hpfrag, hproj_b, h_out, N);
}